// Round 4
// baseline (273.034 us; speedup 1.0000x reference)
//
#include <hip/hip_runtime.h>

// CustomRNN: B=2048, T=512, I=1, H=64. One wave per batch.
// Evolution:
//  R0: full-h LDS broadcast (16 ds_read_b128/step) -> LDS-BW-bound, 172us.
//  R2: 4-way K-split + shfl_xor butterfly -> 158us. Latency+issue bound:
//      VALUBusy 61% @ 740cy/step/SIMD => ~450cy VALU issue (bloated
//      lowering) + ~290cy un-hidden serial latency (ds_read ~120, two
//      serial bpermute levels ~240, write->barrier->read ~150).
//  R1/R3: permlane32/16_swap reduce-scatter -> bit-identical absmax 0.44
//      both rounds (= max|ref|, i.e. output likely never written) ->
//      permlane semantics unverifiable here; abandoned.
//  R4 (this): readlane scheme. Lane l owns row l fully (64 weights in 64
//      VGPRs). h broadcast via 64 v_readlane_b32 (immediate lane index,
//      wave-uniform SGPR) + v_fmac_f32 with SGPR operand. After tanh,
//      hcur on lane l IS h[l] for the next step: no LDS h, no round-trip,
//      no butterfly, no barriers in the hot loop. Correct by construction
//      (no lane-mapping guesses). Expected issue-bound: ~280cy/wave/step.

typedef float v4f __attribute__((ext_vector_type(4)));

#define WPB 4  // waves (== batches) per block

__global__ __launch_bounds__(WPB * 64)
__attribute__((amdgpu_waves_per_eu(2, 2)))  // pin VGPR budget: weight cache
void rnn_fused(
    const float* __restrict__ x,      // [B, T, 1]
    const float* __restrict__ W_ih,   // [64, 1]
    const float* __restrict__ W_hh,   // [64, 64]
    const float* __restrict__ b_ih,   // [64]
    const float* __restrict__ b_hh,   // [64]
    const float* __restrict__ fc_w,   // [1, 64]
    const float* __restrict__ fc_b,   // [1]
    float* __restrict__ out,          // [B, 1]
    int B, int T)
{
    const int lane  = threadIdx.x & 63;
    const int wv    = threadIdx.x >> 6;
    const int batch = blockIdx.x * WPB + wv;
    if (batch >= B) return;  // B % WPB == 0 in practice; no block sync used

    __shared__ __align__(16) float xs[WPB][64];

    // Lane l caches W_hh row l as 64 scalar VGPRs (fully unrolled => static
    // indexing => registers, not scratch).
    float w[64];
    {
        const v4f* wrow = (const v4f*)(W_hh + lane * 64);
#pragma unroll
        for (int i = 0; i < 16; ++i) {
            const v4f t = wrow[i];
            w[4 * i + 0] = t.x;
            w[4 * i + 1] = t.y;
            w[4 * i + 2] = t.z;
            w[4 * i + 3] = t.w;
        }
    }
    const float wih_j  = W_ih[lane];
    const float bias_j = b_ih[lane] + b_hh[lane];

    const float* xb = x + (size_t)batch * T;

    float hcur = 0.0f;  // lane l holds h[l]; no LDS mirror needed

    // One RNN step: a[l] = x*W_ih[l] + bias[l] + sum_k W_hh[l,k]*h[k];
    // h[k] fetched as wave-uniform SGPR via readlane(k) — pure VALU.
    auto step = [&](float xv) {
        const int hbits = __float_as_int(hcur);
        float a0 = __builtin_fmaf(xv, wih_j, bias_j);
        float a1 = 0.0f, a2 = 0.0f, a3 = 0.0f;
#pragma unroll
        for (int k = 0; k < 64; k += 4) {
            const float h0 = __int_as_float(__builtin_amdgcn_readlane(hbits, k + 0));
            const float h1 = __int_as_float(__builtin_amdgcn_readlane(hbits, k + 1));
            const float h2 = __int_as_float(__builtin_amdgcn_readlane(hbits, k + 2));
            const float h3 = __int_as_float(__builtin_amdgcn_readlane(hbits, k + 3));
            a0 = __builtin_fmaf(h0, w[k + 0], a0);
            a1 = __builtin_fmaf(h1, w[k + 1], a1);
            a2 = __builtin_fmaf(h2, w[k + 2], a2);
            a3 = __builtin_fmaf(h3, w[k + 3], a3);
        }
        const float a = (a0 + a1) + (a2 + a3);

        // tanh(a) = sign(a) * (1 - e) / (1 + e),  e = exp(-2|a|)
        const float ax = __builtin_fabsf(a);
        const float e  = __builtin_amdgcn_exp2f(ax * -2.885390082f); // exp(-2ax)
        const float rc = __builtin_amdgcn_rcpf(1.0f + e);
        hcur = __builtin_copysignf((1.0f - e) * rc, a);
    };

    for (int t0 = 0; t0 < T; t0 += 64) {
        const int rem = T - t0;
        // Stage up to 64 input scalars for this batch (coalesced 256B load).
        xs[wv][lane] = (lane < rem) ? xb[t0 + lane] : 0.0f;
        __builtin_amdgcn_wave_barrier();   // order staging before reads

        if (rem >= 64) {
            const v4f* xs4 = (const v4f*)(&xs[wv][0]);
            for (int t4 = 0; t4 < 16; ++t4) {
                const v4f xq = xs4[t4];  // one broadcast b128 per 4 steps
                step(xq.x);
                step(xq.y);
                step(xq.z);
                step(xq.w);
            }
        } else {
            for (int tt = 0; tt < rem; ++tt) step(xs[wv][tt]);
        }
        __builtin_amdgcn_wave_barrier();   // reads done before next staging
    }

    // fc: out[b] = sum_j h[j] * fc_w[j] + fc_b   (lane j holds h[j])
    float v = hcur * fc_w[lane];
#pragma unroll
    for (int off = 32; off > 0; off >>= 1)
        v += __shfl_xor(v, off, 64);
    if (lane == 0) out[batch] = v + fc_b[0];
}

extern "C" void kernel_launch(void* const* d_in, const int* in_sizes, int n_in,
                              void* d_out, int out_size, void* d_ws, size_t ws_size,
                              hipStream_t stream) {
    const float* x    = (const float*)d_in[0];
    const float* W_ih = (const float*)d_in[1];
    const float* W_hh = (const float*)d_in[2];
    const float* b_ih = (const float*)d_in[3];
    const float* b_hh = (const float*)d_in[4];
    const float* fc_w = (const float*)d_in[5];
    const float* fc_b = (const float*)d_in[6];
    float* out = (float*)d_out;

    const int B = out_size;          // output is [B, 1]
    const int T = in_sizes[0] / B;   // I == 1, so x has B*T elements

    const int blocks = (B + WPB - 1) / WPB;
    rnn_fused<<<blocks, WPB * 64, 0, stream>>>(x, W_ih, W_hh, b_ih, b_hh,
                                               fc_w, fc_b, out, B, T);
}

// Round 5
// 177.602 us; speedup vs baseline: 1.5373x; 1.5373x over previous
//
#include <hip/hip_runtime.h>

// CustomRNN: B=2048, T=512, I=1, H=64. One wave per batch.
// Evolution:
//  R0: full-h LDS broadcast (16 ds_read_b128/step), 172us. issue+latency.
//  R2: 4-way K-split (seg = lane>>4) + shfl_xor(32/16) butterfly, 158us.
//      Chain-bound: two serial ds_bpermute hops (~240cy) + LDS round-trip.
//  R4: readlane broadcast -> 228us. 64 readlane + scalar FMAs doubled
//      issue (VALUBusy 83%). Reverted.
//  R1/R3: permlane32/16_swap -> absmax 0.44 (= max|ref|) both tries;
//      unverifiable semantics. Abandoned.
//  R5 (this): QUAD-LOCAL butterfly. Lane l owns k-segment p = l&3
//      (h[16p..16p+16)) and accumulates partial dots for rows
//      {l, l^1, l^2, l^3} (its quad's row window). Reduce-scatter is two
//      v_mov_b32_dpp quad_perm levels (xor1=0xB1, xor2=0x4E) + adds —
//      pure VALU (~2cy hops), replacing both LDS-latency bpermute hops.
//      Mapping verified: z(l) = a[l]. Fallback __shfl_xor(.,1/2) has the
//      IDENTICAL mapping (xor of lane bits 0-1 stays in-quad), so the
//      layout is not coupled to DPP behavior.
// Chain/step: ds_read seg (~120) + fma depth (~32) + quad butterfly (~20)
//   + tanh (~25) + write->read turnaround (~150) ~= 340cy vs R2's ~580.

typedef float v2f __attribute__((ext_vector_type(2)));
typedef float v4f __attribute__((ext_vector_type(4)));

#define WPB 4  // waves (== batches) per block

#define DPP_XOR1 0xB1  // quad_perm:[1,0,3,2]
#define DPP_XOR2 0x4E  // quad_perm:[2,3,0,1]

#if __has_builtin(__builtin_amdgcn_mov_dpp)
template <int CTRL>
__device__ __forceinline__ float qperm(float x) {
    return __int_as_float(__builtin_amdgcn_mov_dpp(
        __float_as_int(x), CTRL, 0xF, 0xF, true));
}
#else
template <int CTRL>
__device__ __forceinline__ float qperm(float x) {
    // identical lane mapping: xor on lane-id bits 0-1
    return __shfl_xor(x, (CTRL == DPP_XOR1) ? 1 : 2, 64);
}
#endif

__global__ __launch_bounds__(WPB * 64)
__attribute__((amdgpu_waves_per_eu(2, 2)))  // pin VGPR budget: weight cache
void rnn_fused(
    const float* __restrict__ x,      // [B, T, 1]
    const float* __restrict__ W_ih,   // [64, 1]
    const float* __restrict__ W_hh,   // [64, 64]
    const float* __restrict__ b_ih,   // [64]
    const float* __restrict__ b_hh,   // [64]
    const float* __restrict__ fc_w,   // [1, 64]
    const float* __restrict__ fc_b,   // [1]
    float* __restrict__ out,          // [B, 1]
    int B, int T)
{
    const int lane  = threadIdx.x & 63;
    const int wv    = threadIdx.x >> 6;
    const int batch = blockIdx.x * WPB + wv;
    if (batch >= B) return;  // no block-wide sync anywhere; early exit safe

    const int p = lane & 3;    // k-segment: k in [16p, 16p+16)

    __shared__ __align__(16) float hs[WPB][64];
    __shared__ __align__(16) float xs[WPB][64];

    // Rows accumulated by this lane (quad-local window): l, l^1, l^2, l^3.
    const int rA = lane;
    const int rB = lane ^ 1;
    const int rC = lane ^ 2;
    const int rD = lane ^ 3;

    // 4 rows x 16 weights = 64 weights/lane as 32 x v2f (64 VGPRs).
    v2f wA[8], wB[8], wC[8], wD[8];
    {
        const v4f* pA = (const v4f*)(W_hh + rA * 64 + 16 * p);
        const v4f* pB = (const v4f*)(W_hh + rB * 64 + 16 * p);
        const v4f* pC = (const v4f*)(W_hh + rC * 64 + 16 * p);
        const v4f* pD = (const v4f*)(W_hh + rD * 64 + 16 * p);
#pragma unroll
        for (int c = 0; c < 4; ++c) {
            v4f tA = pA[c], tB = pB[c], tC = pC[c], tD = pD[c];
            wA[2*c]   = __builtin_shufflevector(tA, tA, 0, 1);
            wA[2*c+1] = __builtin_shufflevector(tA, tA, 2, 3);
            wB[2*c]   = __builtin_shufflevector(tB, tB, 0, 1);
            wB[2*c+1] = __builtin_shufflevector(tB, tB, 2, 3);
            wC[2*c]   = __builtin_shufflevector(tC, tC, 0, 1);
            wC[2*c+1] = __builtin_shufflevector(tC, tC, 2, 3);
            wD[2*c]   = __builtin_shufflevector(tD, tD, 0, 1);
            wD[2*c+1] = __builtin_shufflevector(tD, tD, 2, 3);
        }
    }
    const float wih_j  = W_ih[lane];            // final a[j] lands on lane j
    const float bias_j = b_ih[lane] + b_hh[lane];

    const float* xb = x + (size_t)batch * T;

    hs[wv][lane] = 0.0f;
    __builtin_amdgcn_wave_barrier();

    float hcur = 0.0f;  // lane l holds h[l], mirrored in hs[wv][lane]

    auto step = [&](float xv) {
        // Read this lane's 16-float h segment: 4 ds_read_b128.
        // 4 distinct 16B addrs x 16-lane broadcast; p/p^2 alias banks
        // 2-way which is free (m136).
        const v4f* h4 = (const v4f*)(&hs[wv][p * 16]);
        v2f pAa = {0.f, 0.f}, pBa = {0.f, 0.f}, pCa = {0.f, 0.f}, pDa = {0.f, 0.f};
#pragma unroll
        for (int c = 0; c < 4; ++c) {
            const v4f hv  = h4[c];
            const v2f hlo = __builtin_shufflevector(hv, hv, 0, 1);
            const v2f hhi = __builtin_shufflevector(hv, hv, 2, 3);
            pAa = __builtin_elementwise_fma(hlo, wA[2*c],   pAa);
            pBa = __builtin_elementwise_fma(hlo, wB[2*c],   pBa);
            pCa = __builtin_elementwise_fma(hlo, wC[2*c],   pCa);
            pDa = __builtin_elementwise_fma(hlo, wD[2*c],   pDa);
            pAa = __builtin_elementwise_fma(hhi, wA[2*c+1], pAa);
            pBa = __builtin_elementwise_fma(hhi, wB[2*c+1], pBa);
            pCa = __builtin_elementwise_fma(hhi, wC[2*c+1], pCa);
            pDa = __builtin_elementwise_fma(hhi, wD[2*c+1], pDa);
        }
        const float sA = pAa.x + pAa.y, sB = pBa.x + pBa.y;
        const float sC = pCa.x + pCa.y, sD = pDa.x + pDa.y;
        // Quad-local reduce-scatter, all VALU:
        //   u0 = row l      over segs {p, p^1}
        //   u1 = row l^2    over segs {p, p^1}
        //   z  = row l      over all 4 segs  -> a[l] on lane l
        const float u0 = sA + qperm<DPP_XOR1>(sB);
        const float u1 = sC + qperm<DPP_XOR1>(sD);
        const float z  = u0 + qperm<DPP_XOR2>(u1);
        // Per-row bias/x term strictly AFTER reduction.
        const float a  = z + __builtin_fmaf(xv, wih_j, bias_j);

        // tanh(a) = sign(a) * (1 - e) / (1 + e),  e = exp(-2|a|)
        const float ax = __builtin_fabsf(a);
        const float e  = __builtin_amdgcn_exp2f(ax * -2.885390082f); // exp(-2ax)
        const float rc = __builtin_amdgcn_rcpf(1.0f + e);
        hcur = __builtin_copysignf((1.0f - e) * rc, a);

        __builtin_amdgcn_wave_barrier();   // all reads of this step done
        hs[wv][lane] = hcur;
        __builtin_amdgcn_wave_barrier();   // write ordered before next reads
    };

    for (int t0 = 0; t0 < T; t0 += 64) {
        const int rem = T - t0;
        // Stage up to 64 input scalars for this batch (coalesced 256B load).
        xs[wv][lane] = (lane < rem) ? xb[t0 + lane] : 0.0f;
        __builtin_amdgcn_wave_barrier();

        if (rem >= 64) {
            const v4f* xs4 = (const v4f*)(&xs[wv][0]);
            for (int t4 = 0; t4 < 16; ++t4) {
                const v4f xq = xs4[t4];  // one broadcast b128 per 4 steps
                step(xq.x);
                step(xq.y);
                step(xq.z);
                step(xq.w);
            }
        } else {
            for (int tt = 0; tt < rem; ++tt) step(xs[wv][tt]);
        }
    }

    // fc: out[b] = sum_j h[j] * fc_w[j] + fc_b   (lane j holds h[j])
    float v = hcur * fc_w[lane];
#pragma unroll
    for (int off = 32; off > 0; off >>= 1)
        v += __shfl_xor(v, off, 64);
    if (lane == 0) out[batch] = v + fc_b[0];
}

extern "C" void kernel_launch(void* const* d_in, const int* in_sizes, int n_in,
                              void* d_out, int out_size, void* d_ws, size_t ws_size,
                              hipStream_t stream) {
    const float* x    = (const float*)d_in[0];
    const float* W_ih = (const float*)d_in[1];
    const float* W_hh = (const float*)d_in[2];
    const float* b_ih = (const float*)d_in[3];
    const float* b_hh = (const float*)d_in[4];
    const float* fc_w = (const float*)d_in[5];
    const float* fc_b = (const float*)d_in[6];
    float* out = (float*)d_out;

    const int B = out_size;          // output is [B, 1]
    const int T = in_sizes[0] / B;   // I == 1, so x has B*T elements

    const int blocks = (B + WPB - 1) / WPB;
    rnn_fused<<<blocks, WPB * 64, 0, stream>>>(x, W_ih, W_hh, b_ih, b_hh,
                                               fc_w, fc_b, out, B, T);
}